// Round 1
// baseline (2521.248 us; speedup 1.0000x reference)
//
#include <hip/hip_runtime.h>

// MLP_1314259992962: 16x (Linear(128,128)+ReLU) chain + Linear(128,2), fp32 in/out.
// Strategy: fused persistent-register kernel, bf16 hi/lo split (3 MFMA terms) for
// ~fp32 accuracy at bf16 matrix-core rate. 256 rows/block, 64 rows/wave,
// mfma_f32_16x16x32_bf16. Weights pre-split+fragment-shuffled into d_ws (1 MB).
// LDS only for per-layer C->A transpose of activations (stride 132 anti-conflict,
// XOR-8 block swizzle).

#define LAYERS 16
#define SLD    132   // scratch row stride in dwords (128 + 4 pad)

typedef __bf16 bf16x8 __attribute__((ext_vector_type(8)));
typedef float  f32x4  __attribute__((ext_vector_type(4)));

__device__ __forceinline__ unsigned short f2bf(float f) {
  unsigned u = __float_as_uint(f);
  u += 0x7fffu + ((u >> 16) & 1u);       // round-to-nearest-even
  return (unsigned short)(u >> 16);
}

#if __has_builtin(__builtin_amdgcn_cvt_pk_bf16_f32)
typedef __bf16 bf16x2 __attribute__((ext_vector_type(2)));
__device__ __forceinline__ unsigned pkbf(float a, float b) {
  // low 16 = bf16(a), high 16 = bf16(b)  (pk family convention: D.lo = S0)
  return __builtin_bit_cast(unsigned, __builtin_amdgcn_cvt_pk_bf16_f32(a, b));
}
#else
__device__ __forceinline__ unsigned pkbf(float a, float b) {
  return (((unsigned)f2bf(b)) << 16) | (unsigned)f2bf(a);
}
#endif

// split (a,b) into packed-hi word and packed-lo word (bf16 pairs)
__device__ __forceinline__ void split2(float a, float b, unsigned &hw, unsigned &lw) {
  unsigned hp = pkbf(a, b);
  float la = a - __uint_as_float(hp << 16);
  float lb = b - __uint_as_float(hp & 0xffff0000u);
  hw = hp;
  lw = pkbf(la, lb);
}

// reconstruct fp32 from packed (hi<<16)|lo word
__device__ __forceinline__ float upk(unsigned w) {
  return __uint_as_float(w & 0xffff0000u) + __uint_as_float(w << 16);
}

// ---------------------------------------------------------------------------
// Prep: W fp32 [16][128][128] -> fragment-ordered bf16 hi/lo in ws.
// Layout (dwords): [l][fragid = ((nt*4+ks)*2+term)][lane][d], 16384 dwords/layer.
// B-frag element map: n = nt*16 + (lane&15); k = ks*32 + (lane>>4)*8 + 2d + {0,1};
// value = W[l][n][k]  (torch Linear: y = x @ W^T).
// ---------------------------------------------------------------------------
__global__ void prep_w(const float* __restrict__ W, unsigned* __restrict__ wf) {
  int t = blockIdx.x * 256 + threadIdx.x;    // 0 .. 262143
  int l     = t >> 14;
  int r     = t & 16383;
  int fi    = r >> 8;                        // 0..63
  int inner = r & 255;
  int lanei = inner >> 2;
  int d     = inner & 3;
  int term  = fi & 1;
  int ntks  = fi >> 1;
  int nt = ntks >> 2, ks = ntks & 3;
  int n = nt * 16 + (lanei & 15);
  int k = ks * 32 + (lanei >> 4) * 8 + d * 2;
  const float* wp = W + ((l * 128 + n) * 128 + k);
  float w0 = wp[0], w1 = wp[1];
  unsigned hp = pkbf(w0, w1);
  unsigned res;
  if (term == 0) {
    res = hp;
  } else {
    float h0 = __uint_as_float(hp << 16);
    float h1 = __uint_as_float(hp & 0xffff0000u);
    res = pkbf(w0 - h0, w1 - h1);
  }
  wf[t] = res;
}

// ---------------------------------------------------------------------------
// Main fused MLP kernel. grid = 4096 blocks x 256 threads. 1 block/CU (LDS 132KB).
// ---------------------------------------------------------------------------
__launch_bounds__(256, 1)
__global__ void mlp_kernel(const unsigned* __restrict__ wf,
                           const float* __restrict__ bias,
                           const float* __restrict__ x,
                           const float* __restrict__ wout,
                           const float* __restrict__ bout,
                           float* __restrict__ out) {
  __shared__ unsigned sS[4 * 64 * SLD];      // 4 waves x 64 rows x 132 dwords
  const int tid  = threadIdx.x;
  const int wave = tid >> 6;
  const int lane = tid & 63;
  const int c    = lane & 15;                // A-row / B-col / C-col lane index
  const int q    = lane >> 4;                // quad
  const int s    = (c >> 2) & 3;             // reader swizzle key ((row>>2)&3)
  const long rowbase = (long)blockIdx.x * 256 + wave * 64;

  unsigned* sw = sS + wave * (64 * SLD);

  // A fragments (activations), hi/lo packed bf16 pairs: [mt][ks], 8 bf16 each.
  uint4 a_hi[4][4];
  uint4 a_lo[4][4];

  // ---- layer-0 input: load x rows, split into A fragments ----
  {
    const float* xb = x + rowbase * 128;
#pragma unroll
    for (int mt = 0; mt < 4; ++mt) {
      const float* xr = xb + (mt * 16 + c) * 128 + q * 8;
#pragma unroll
      for (int ks = 0; ks < 4; ++ks) {
        float4 v0 = *(const float4*)(xr + ks * 32);
        float4 v1 = *(const float4*)(xr + ks * 32 + 4);
        uint4 hh, ll;
        split2(v0.x, v0.y, hh.x, ll.x);
        split2(v0.z, v0.w, hh.y, ll.y);
        split2(v1.x, v1.y, hh.z, ll.z);
        split2(v1.z, v1.w, hh.w, ll.w);
        a_hi[mt][ks] = hh;
        a_lo[mt][ks] = ll;
      }
    }
  }

#pragma unroll 1
  for (int l = 0; l < LAYERS; ++l) {
    if (l > 0) {
      __syncthreads();  // order prev-layer scratch writes before reads (cross-lane)
      // A-phase: read packed h from scratch, unpack to hi/lo frags via v_perm
#pragma unroll
      for (int mt = 0; mt < 4; ++mt) {
        const unsigned* rowp = sw + (mt * 16 + c) * SLD;
#pragma unroll
        for (int ks = 0; ks < 4; ++ks) {
          int fb = ks * 32 + 8 * (q ^ s);    // swizzled f' base
          uint4 p0 = *(const uint4*)(rowp + fb);
          uint4 p1 = *(const uint4*)(rowp + fb + 4);
          uint4 hh, ll;
          hh.x = __builtin_amdgcn_perm(p0.y, p0.x, 0x07060302u);
          ll.x = __builtin_amdgcn_perm(p0.y, p0.x, 0x05040100u);
          hh.y = __builtin_amdgcn_perm(p0.w, p0.z, 0x07060302u);
          ll.y = __builtin_amdgcn_perm(p0.w, p0.z, 0x05040100u);
          hh.z = __builtin_amdgcn_perm(p1.y, p1.x, 0x07060302u);
          ll.z = __builtin_amdgcn_perm(p1.y, p1.x, 0x05040100u);
          hh.w = __builtin_amdgcn_perm(p1.w, p1.z, 0x07060302u);
          ll.w = __builtin_amdgcn_perm(p1.w, p1.z, 0x05040100u);
          a_hi[mt][ks] = hh;
          a_lo[mt][ks] = ll;
        }
      }
    }

    const uint4* wl = (const uint4*)(wf + l * 16384);
    float bv[8];
#pragma unroll
    for (int nt = 0; nt < 8; ++nt) bv[nt] = bias[l * 128 + nt * 16 + c];

#pragma unroll
    for (int nt = 0; nt < 8; ++nt) {
      // B fragments for this output column block: straight from L2, coalesced.
      uint4 bh[4], bl[4];
#pragma unroll
      for (int ks = 0; ks < 4; ++ks) {
        bh[ks] = wl[((nt * 4 + ks) * 2 + 0) * 64 + lane];
        bl[ks] = wl[((nt * 4 + ks) * 2 + 1) * 64 + lane];
      }
      f32x4 acc[4];
#pragma unroll
      for (int mt = 0; mt < 4; ++mt) {
        f32x4 a0 = {bv[nt], bv[nt], bv[nt], bv[nt]};  // bias pre-loaded into acc
        acc[mt] = a0;
      }
#pragma unroll
      for (int ks = 0; ks < 4; ++ks) {
        bf16x8 Bh = __builtin_bit_cast(bf16x8, bh[ks]);
        bf16x8 Bl = __builtin_bit_cast(bf16x8, bl[ks]);
#pragma unroll
        for (int mt = 0; mt < 4; ++mt) {
          bf16x8 Ah = __builtin_bit_cast(bf16x8, a_hi[mt][ks]);
          bf16x8 Al = __builtin_bit_cast(bf16x8, a_lo[mt][ks]);
          acc[mt] = __builtin_amdgcn_mfma_f32_16x16x32_bf16(Ah, Bh, acc[mt], 0, 0, 0);
          acc[mt] = __builtin_amdgcn_mfma_f32_16x16x32_bf16(Ah, Bl, acc[mt], 0, 0, 0);
          acc[mt] = __builtin_amdgcn_mfma_f32_16x16x32_bf16(Al, Bh, acc[mt], 0, 0, 0);
        }
      }
      // epilogue: relu, split to hi/lo, pack per-element (hi<<16|lo), write scratch
#pragma unroll
      for (int mt = 0; mt < 4; ++mt) {
        int fsw = (nt * 16 + c) ^ (8 * q);   // writer swizzle key = q
        unsigned* wp = sw + (mt * 16 + q * 4) * SLD + fsw;
        float e0 = fmaxf(acc[mt][0], 0.0f);
        float e1 = fmaxf(acc[mt][1], 0.0f);
        float e2 = fmaxf(acc[mt][2], 0.0f);
        float e3 = fmaxf(acc[mt][3], 0.0f);
        unsigned hp, lp, hp2, lp2;
        split2(e0, e1, hp, lp);
        split2(e2, e3, hp2, lp2);
        wp[0 * SLD] = (hp << 16) | (lp & 0xffffu);
        wp[1 * SLD] = (hp & 0xffff0000u) | (lp >> 16);
        wp[2 * SLD] = (hp2 << 16) | (lp2 & 0xffffu);
        wp[3 * SLD] = (hp2 & 0xffff0000u) | (lp2 >> 16);
      }
    }
  }

  // ---- final Linear(128,2) from scratch (fp32 math) ----
  __syncthreads();
  float bo0 = bout[0], bo1 = bout[1];
#pragma unroll
  for (int mt = 0; mt < 4; ++mt) {
    const unsigned* rowp = sw + (mt * 16 + c) * SLD;
    float s0 = 0.0f, s1 = 0.0f;
#pragma unroll
    for (int bb = 0; bb < 4; ++bb) {
      int fpb = q * 32 + bb * 8;             // stored (swizzled) f' base
      int fab = q * 32 + (bb ^ s) * 8;       // actual f base
      uint4 h0 = *(const uint4*)(rowp + fpb);
      uint4 h1 = *(const uint4*)(rowp + fpb + 4);
      float4 w00 = *(const float4*)(wout + fab);
      float4 w01 = *(const float4*)(wout + fab + 4);
      float4 w10 = *(const float4*)(wout + 128 + fab);
      float4 w11 = *(const float4*)(wout + 128 + fab + 4);
      float xv;
      xv = upk(h0.x); s0 = fmaf(xv, w00.x, s0); s1 = fmaf(xv, w10.x, s1);
      xv = upk(h0.y); s0 = fmaf(xv, w00.y, s0); s1 = fmaf(xv, w10.y, s1);
      xv = upk(h0.z); s0 = fmaf(xv, w00.z, s0); s1 = fmaf(xv, w10.z, s1);
      xv = upk(h0.w); s0 = fmaf(xv, w00.w, s0); s1 = fmaf(xv, w10.w, s1);
      xv = upk(h1.x); s0 = fmaf(xv, w01.x, s0); s1 = fmaf(xv, w11.x, s1);
      xv = upk(h1.y); s0 = fmaf(xv, w01.y, s0); s1 = fmaf(xv, w11.y, s1);
      xv = upk(h1.z); s0 = fmaf(xv, w01.z, s0); s1 = fmaf(xv, w11.z, s1);
      xv = upk(h1.w); s0 = fmaf(xv, w01.w, s0); s1 = fmaf(xv, w11.w, s1);
    }
    // reduce the 4 quads (k-partials) of each row
    s0 += __shfl_xor(s0, 16); s0 += __shfl_xor(s0, 32);
    s1 += __shfl_xor(s1, 16); s1 += __shfl_xor(s1, 32);
    if (q == 0) {
      long r = rowbase + mt * 16 + c;
      float2 o;
      o.x = s0 + bo0;
      o.y = s1 + bo1;
      *(float2*)(out + r * 2) = o;
    }
  }
}

extern "C" void kernel_launch(void* const* d_in, const int* in_sizes, int n_in,
                              void* d_out, int out_size, void* d_ws, size_t ws_size,
                              hipStream_t stream) {
  (void)in_sizes; (void)n_in; (void)out_size; (void)ws_size;
  const float* x    = (const float*)d_in[0];   // [1048576][128]
  const float* W    = (const float*)d_in[1];   // [16][128][128]
  const float* b    = (const float*)d_in[2];   // [16][128]
  const float* wout = (const float*)d_in[3];   // [2][128]
  const float* bout = (const float*)d_in[4];   // [2]
  float* out = (float*)d_out;                  // [1048576][2]
  unsigned* wf = (unsigned*)d_ws;              // 1 MB fragment-ordered split weights

  prep_w<<<dim3(1024), dim3(256), 0, stream>>>(W, wf);
  mlp_kernel<<<dim3(4096), dim3(256), 0, stream>>>(wf, b, x, wout, bout, out);
}

// Round 2
// 2177.924 us; speedup vs baseline: 1.1576x; 1.1576x over previous
//
#include <hip/hip_runtime.h>

// MLP_1314259992962: 16x (Linear(128,128)+ReLU) chain + Linear(128,2), fp32 in/out.
// R2: same structure as R1 (64 rows/wave, 4 waves/block, 3-term bf16 hi/lo split,
// mfma_f32_16x16x32_bf16) with latency fixes:
//   - ALL __syncthreads removed (LDS scratch is wave-private; intra-wave lgkmcnt
//     ordering is enough)
//   - explicit B-fragment double-buffer: nt+1's 8 loads issue before nt's MFMAs;
//     next layer's nt=0 issues before the transpose phase
//   - next layer's bias prefetched during nt=0
// R1 evidence: 19.4K cy/layer vs ~7.5K accounted -> exposed L2 latency at
// 1 wave/SIMD (VGPR=132 shows compiler kept no prefetch registers).

#define LAYERS 16
#define SLD    132   // scratch row stride in dwords (128 + 4 pad)

typedef __bf16 bf16x8 __attribute__((ext_vector_type(8)));
typedef float  f32x4  __attribute__((ext_vector_type(4)));

__device__ __forceinline__ unsigned short f2bf(float f) {
  unsigned u = __float_as_uint(f);
  u += 0x7fffu + ((u >> 16) & 1u);       // round-to-nearest-even
  return (unsigned short)(u >> 16);
}

#if __has_builtin(__builtin_amdgcn_cvt_pk_bf16_f32)
typedef __bf16 bf16x2 __attribute__((ext_vector_type(2)));
__device__ __forceinline__ unsigned pkbf(float a, float b) {
  // low 16 = bf16(a), high 16 = bf16(b)
  return __builtin_bit_cast(unsigned, __builtin_amdgcn_cvt_pk_bf16_f32(a, b));
}
#else
__device__ __forceinline__ unsigned pkbf(float a, float b) {
  return (((unsigned)f2bf(b)) << 16) | (unsigned)f2bf(a);
}
#endif

// split (a,b) into packed-hi word and packed-lo word (bf16 pairs)
__device__ __forceinline__ void split2(float a, float b, unsigned &hw, unsigned &lw) {
  unsigned hp = pkbf(a, b);
  float la = a - __uint_as_float(hp << 16);
  float lb = b - __uint_as_float(hp & 0xffff0000u);
  hw = hp;
  lw = pkbf(la, lb);
}

// reconstruct fp32 from packed (hi<<16)|lo word
__device__ __forceinline__ float upk(unsigned w) {
  return __uint_as_float(w & 0xffff0000u) + __uint_as_float(w << 16);
}

// ---------------------------------------------------------------------------
// Prep: W fp32 [16][128][128] -> fragment-ordered bf16 hi/lo in ws.
// Layout (dwords): [l][fragid = ((nt*4+ks)*2+term)][lane][d], 16384 dwords/layer.
// B-frag element map: n = nt*16 + (lane&15); k = ks*32 + (lane>>4)*8 + 2d + {0,1};
// value = W[l][n][k]  (torch Linear: y = x @ W^T).
// ---------------------------------------------------------------------------
__global__ void prep_w(const float* __restrict__ W, unsigned* __restrict__ wf) {
  int t = blockIdx.x * 256 + threadIdx.x;    // 0 .. 262143
  int l     = t >> 14;
  int r     = t & 16383;
  int fi    = r >> 8;                        // 0..63
  int inner = r & 255;
  int lanei = inner >> 2;
  int d     = inner & 3;
  int term  = fi & 1;
  int ntks  = fi >> 1;
  int nt = ntks >> 2, ks = ntks & 3;
  int n = nt * 16 + (lanei & 15);
  int k = ks * 32 + (lanei >> 4) * 8 + d * 2;
  const float* wp = W + ((l * 128 + n) * 128 + k);
  float w0 = wp[0], w1 = wp[1];
  unsigned hp = pkbf(w0, w1);
  unsigned res;
  if (term == 0) {
    res = hp;
  } else {
    float h0 = __uint_as_float(hp << 16);
    float h1 = __uint_as_float(hp & 0xffff0000u);
    res = pkbf(w0 - h0, w1 - h1);
  }
  wf[t] = res;
}

// ---------------------------------------------------------------------------
// Main fused MLP kernel. grid = 4096 blocks x 256 threads. 1 block/CU (LDS 132KB).
// ---------------------------------------------------------------------------
__launch_bounds__(256, 1)
__global__ void mlp_kernel(const unsigned* __restrict__ wf,
                           const float* __restrict__ bias,
                           const float* __restrict__ x,
                           const float* __restrict__ wout,
                           const float* __restrict__ bout,
                           float* __restrict__ out) {
  __shared__ unsigned sS[4 * 64 * SLD];      // 4 waves x 64 rows x 132 dwords
  const int tid  = threadIdx.x;
  const int wave = tid >> 6;
  const int lane = tid & 63;
  const int c    = lane & 15;                // A-row / B-col / C-col lane index
  const int q    = lane >> 4;                // quad
  const int s    = (c >> 2) & 3;             // reader swizzle key ((row>>2)&3)
  const long rowbase = (long)blockIdx.x * 256 + wave * 64;

  unsigned* sw = sS + wave * (64 * SLD);

  // A fragments (activations), hi/lo packed bf16 pairs: [mt][ks], 8 bf16 each.
  uint4 a_hi[4][4];
  uint4 a_lo[4][4];

  // B-fragment double buffer (8 uint4 per slot: 4 ks x {hi,lo})
  uint4 bhb[2][4], blb[2][4];
  {
    const uint4* wl0 = (const uint4*)wf;
#pragma unroll
    for (int ks = 0; ks < 4; ++ks) {
      bhb[0][ks] = wl0[((0 * 4 + ks) * 2 + 0) * 64 + lane];
      blb[0][ks] = wl0[((0 * 4 + ks) * 2 + 1) * 64 + lane];
    }
  }
  float bv[8], bv_n[8];
#pragma unroll
  for (int nt = 0; nt < 8; ++nt) bv[nt] = bias[nt * 16 + c];

  // ---- layer-0 input: load x rows, split into A fragments ----
  {
    const float* xb = x + rowbase * 128;
#pragma unroll
    for (int mt = 0; mt < 4; ++mt) {
      const float* xr = xb + (mt * 16 + c) * 128 + q * 8;
#pragma unroll
      for (int ks = 0; ks < 4; ++ks) {
        float4 v0 = *(const float4*)(xr + ks * 32);
        float4 v1 = *(const float4*)(xr + ks * 32 + 4);
        uint4 hh, ll;
        split2(v0.x, v0.y, hh.x, ll.x);
        split2(v0.z, v0.w, hh.y, ll.y);
        split2(v1.x, v1.y, hh.z, ll.z);
        split2(v1.z, v1.w, hh.w, ll.w);
        a_hi[mt][ks] = hh;
        a_lo[mt][ks] = ll;
      }
    }
  }

#pragma unroll 1
  for (int l = 0; l < LAYERS; ++l) {
    if (l > 0) {
      // A-phase: read packed h from wave-private scratch (no barrier needed),
      // unpack to hi/lo frags via v_perm. Compiler inserts lgkmcnt ordering vs
      // the previous layer's ds_writes.
#pragma unroll
      for (int mt = 0; mt < 4; ++mt) {
        const unsigned* rowp = sw + (mt * 16 + c) * SLD;
#pragma unroll
        for (int ks = 0; ks < 4; ++ks) {
          int fb = ks * 32 + 8 * (q ^ s);    // swizzled f' base
          uint4 p0 = *(const uint4*)(rowp + fb);
          uint4 p1 = *(const uint4*)(rowp + fb + 4);
          uint4 hh, ll;
          hh.x = __builtin_amdgcn_perm(p0.y, p0.x, 0x07060302u);
          ll.x = __builtin_amdgcn_perm(p0.y, p0.x, 0x05040100u);
          hh.y = __builtin_amdgcn_perm(p0.w, p0.z, 0x07060302u);
          ll.y = __builtin_amdgcn_perm(p0.w, p0.z, 0x05040100u);
          hh.z = __builtin_amdgcn_perm(p1.y, p1.x, 0x07060302u);
          ll.z = __builtin_amdgcn_perm(p1.y, p1.x, 0x05040100u);
          hh.w = __builtin_amdgcn_perm(p1.w, p1.z, 0x07060302u);
          ll.w = __builtin_amdgcn_perm(p1.w, p1.z, 0x05040100u);
          a_hi[mt][ks] = hh;
          a_lo[mt][ks] = ll;
        }
      }
    }

    const uint4* wl      = (const uint4*)(wf + l * 16384);
    const uint4* wl_next = (const uint4*)(wf + (l + 1) * 16384);

#pragma unroll
    for (int nt = 0; nt < 8; ++nt) {
      const uint4* bh = bhb[nt & 1];
      const uint4* bl = blb[nt & 1];
      uint4* bh_n = bhb[(nt + 1) & 1];
      uint4* bl_n = blb[(nt + 1) & 1];
      // Prefetch: next nt of this layer, or nt=0 of the next layer. Issued
      // before the MFMA block so the loads fly under the matrix work.
      if (nt < 7) {
#pragma unroll
        for (int ks = 0; ks < 4; ++ks) {
          bh_n[ks] = wl[(((nt + 1) * 4 + ks) * 2 + 0) * 64 + lane];
          bl_n[ks] = wl[(((nt + 1) * 4 + ks) * 2 + 1) * 64 + lane];
        }
      } else if (l < LAYERS - 1) {
#pragma unroll
        for (int ks = 0; ks < 4; ++ks) {
          bh_n[ks] = wl_next[((0 * 4 + ks) * 2 + 0) * 64 + lane];
          bl_n[ks] = wl_next[((0 * 4 + ks) * 2 + 1) * 64 + lane];
        }
      }
      if (nt == 0 && l < LAYERS - 1) {
#pragma unroll
        for (int j = 0; j < 8; ++j) bv_n[j] = bias[(l + 1) * 128 + j * 16 + c];
      }

      f32x4 acc[4];
#pragma unroll
      for (int mt = 0; mt < 4; ++mt) {
        f32x4 a0 = {bv[nt], bv[nt], bv[nt], bv[nt]};  // bias pre-loaded into acc
        acc[mt] = a0;
      }
#pragma unroll
      for (int ks = 0; ks < 4; ++ks) {
        bf16x8 Bh = __builtin_bit_cast(bf16x8, bh[ks]);
        bf16x8 Bl = __builtin_bit_cast(bf16x8, bl[ks]);
#pragma unroll
        for (int mt = 0; mt < 4; ++mt) {
          bf16x8 Ah = __builtin_bit_cast(bf16x8, a_hi[mt][ks]);
          bf16x8 Al = __builtin_bit_cast(bf16x8, a_lo[mt][ks]);
          acc[mt] = __builtin_amdgcn_mfma_f32_16x16x32_bf16(Ah, Bh, acc[mt], 0, 0, 0);
          acc[mt] = __builtin_amdgcn_mfma_f32_16x16x32_bf16(Ah, Bl, acc[mt], 0, 0, 0);
          acc[mt] = __builtin_amdgcn_mfma_f32_16x16x32_bf16(Al, Bh, acc[mt], 0, 0, 0);
        }
      }
      // epilogue: relu, split to hi/lo, pack per-element (hi<<16|lo), write scratch
#pragma unroll
      for (int mt = 0; mt < 4; ++mt) {
        int fsw = (nt * 16 + c) ^ (8 * q);   // writer swizzle key = q
        unsigned* wp = sw + (mt * 16 + q * 4) * SLD + fsw;
        float e0 = fmaxf(acc[mt][0], 0.0f);
        float e1 = fmaxf(acc[mt][1], 0.0f);
        float e2 = fmaxf(acc[mt][2], 0.0f);
        float e3 = fmaxf(acc[mt][3], 0.0f);
        unsigned hp, lp, hp2, lp2;
        split2(e0, e1, hp, lp);
        split2(e2, e3, hp2, lp2);
        wp[0 * SLD] = (hp << 16) | (lp & 0xffffu);
        wp[1 * SLD] = (hp & 0xffff0000u) | (lp >> 16);
        wp[2 * SLD] = (hp2 << 16) | (lp2 & 0xffffu);
        wp[3 * SLD] = (hp2 & 0xffff0000u) | (lp2 >> 16);
      }
    }
    // rotate bias registers for next layer
#pragma unroll
    for (int j = 0; j < 8; ++j) bv[j] = bv_n[j];
  }

  // ---- final Linear(128,2) from wave-private scratch (fp32 math) ----
  float bo0 = bout[0], bo1 = bout[1];
#pragma unroll
  for (int mt = 0; mt < 4; ++mt) {
    const unsigned* rowp = sw + (mt * 16 + c) * SLD;
    float s0 = 0.0f, s1 = 0.0f;
#pragma unroll
    for (int bb = 0; bb < 4; ++bb) {
      int fpb = q * 32 + bb * 8;             // stored (swizzled) f' base
      int fab = q * 32 + (bb ^ s) * 8;       // actual f base
      uint4 h0 = *(const uint4*)(rowp + fpb);
      uint4 h1 = *(const uint4*)(rowp + fpb + 4);
      float4 w00 = *(const float4*)(wout + fab);
      float4 w01 = *(const float4*)(wout + fab + 4);
      float4 w10 = *(const float4*)(wout + 128 + fab);
      float4 w11 = *(const float4*)(wout + 128 + fab + 4);
      float xv;
      xv = upk(h0.x); s0 = fmaf(xv, w00.x, s0); s1 = fmaf(xv, w10.x, s1);
      xv = upk(h0.y); s0 = fmaf(xv, w00.y, s0); s1 = fmaf(xv, w10.y, s1);
      xv = upk(h0.z); s0 = fmaf(xv, w00.z, s0); s1 = fmaf(xv, w10.z, s1);
      xv = upk(h0.w); s0 = fmaf(xv, w00.w, s0); s1 = fmaf(xv, w10.w, s1);
      xv = upk(h1.x); s0 = fmaf(xv, w01.x, s0); s1 = fmaf(xv, w11.x, s1);
      xv = upk(h1.y); s0 = fmaf(xv, w01.y, s0); s1 = fmaf(xv, w11.y, s1);
      xv = upk(h1.z); s0 = fmaf(xv, w01.z, s0); s1 = fmaf(xv, w11.z, s1);
      xv = upk(h1.w); s0 = fmaf(xv, w01.w, s0); s1 = fmaf(xv, w11.w, s1);
    }
    // reduce the 4 quads (k-partials) of each row
    s0 += __shfl_xor(s0, 16); s0 += __shfl_xor(s0, 32);
    s1 += __shfl_xor(s1, 16); s1 += __shfl_xor(s1, 32);
    if (q == 0) {
      long r = rowbase + mt * 16 + c;
      float2 o;
      o.x = s0 + bo0;
      o.y = s1 + bo1;
      *(float2*)(out + r * 2) = o;
    }
  }
}

extern "C" void kernel_launch(void* const* d_in, const int* in_sizes, int n_in,
                              void* d_out, int out_size, void* d_ws, size_t ws_size,
                              hipStream_t stream) {
  (void)in_sizes; (void)n_in; (void)out_size; (void)ws_size;
  const float* x    = (const float*)d_in[0];   // [1048576][128]
  const float* W    = (const float*)d_in[1];   // [16][128][128]
  const float* b    = (const float*)d_in[2];   // [16][128]
  const float* wout = (const float*)d_in[3];   // [2][128]
  const float* bout = (const float*)d_in[4];   // [2]
  float* out = (float*)d_out;                  // [1048576][2]
  unsigned* wf = (unsigned*)d_ws;              // 1 MB fragment-ordered split weights

  prep_w<<<dim3(1024), dim3(256), 0, stream>>>(W, wf);
  mlp_kernel<<<dim3(4096), dim3(256), 0, stream>>>(wf, b, x, wout, bout, out);
}